// Round 12
// baseline (39.642 us; speedup 1.0000x reference)
//
#include <hip/hip_runtime.h>
#include <hip/hip_bf16.h>

// MADPSNet fused, round 12: revert to r10 geometry (M=64, 16 waves, 1 blk/CU
// -- r5/r11 both prove M=32 regresses) + 32x32x16 MFMA for L1-L3.
// Mechanism: at r10's ~26us nothing is BW-saturated (A-LDS 36%, B-L2 25%,
// MFMA 28%) -> still latency/issue-bound. 32x32 MFMA runs ~39cy vs ~19cy:
// same in-flight loads covered by 2x issue time, half the MFMA issue slots,
// half the VALU addressing. Per-FLOP operand traffic unchanged.
//  - L1/L3 (N=512): 32x32, (MG,NG)=(1,16), M4=2 frags, F=1
//  - L2   (N=256): 32x32, (2,8), M4=1, F=1, even/odd acc split (dep chain)
//  - L4   (N=128): 16x16, (2,8) as r10 (N too small for 32-col groups)
//  - swizzle upgraded to sig(row)=(row+(row>>3))&7: uniform bank spread for
//    BOTH 16-row and 32-row readers (plain row&7 would 4-way-conflict 32 rows)
// Carried: packed-B fragment streams, swapped-operand MFMA (C/D transposed ->
// lane = row, 4-consecutive-col groups -> vector epilogue), no hand pipelining.

typedef __attribute__((ext_vector_type(8))) short bf16x8;
typedef __attribute__((ext_vector_type(4))) float f32x4;
typedef __attribute__((ext_vector_type(16))) float f32x16;

__device__ __forceinline__ ushort f2b(float x) {
    __hip_bfloat16 h = __float2bfloat16(x);
    return *reinterpret_cast<ushort*>(&h);
}
__device__ __forceinline__ int sig(int row) { return (row + (row >> 3)) & 7; }

// ---------------------------------------------------------------- prep32 ---
// W[e][K][N] fp32 -> Wp frag order for 32x32x16:
//   dst[((e*(N/32)+cg)*NK + s)*512 + lane*8 + j]
//   col = cg*32 + (lane&31), k = s*16 + (lane>>5)*8 + j, NK = K/16
__global__ __launch_bounds__(256)
void prep32(const float* __restrict__ Ws1, const float* __restrict__ Ws2,
            const float* __restrict__ Wd1,
            ushort* __restrict__ W1p, ushort* __restrict__ W2p,
            ushort* __restrict__ W3p)
{
    const int layer = blockIdx.z, e = blockIdx.y, cg = blockIdx.x;
    const float* W; ushort* Wp; int K, N;
    if (layer == 0)      { W = Ws1; Wp = W1p; K = 256; N = 512; }
    else if (layer == 1) { W = Ws2; Wp = W2p; K = 512; N = 256; }
    else                 { W = Wd1; Wp = W3p; K = 256; N = 512; }
    if (cg >= N / 32) return;
    const int NK = K / 16;
    W += (size_t)e * K * N;

    __shared__ float tile[512][33];
    const int tid = threadIdx.x;
    for (int idx = tid; idx < K * 32; idx += 256)
        tile[idx >> 5][idx & 31] = W[(size_t)(idx >> 5) * N + cg * 32 + (idx & 31)];
    __syncthreads();
    ushort* dst = Wp + (((size_t)e * (N / 32) + cg) * NK) * 512;
    for (int w = tid; w < NK * 64; w += 256) {
        const int s = w >> 6, lane = w & 63;
        const int c  = lane & 31;
        const int kb = s * 16 + ((lane >> 5) << 3);
        bf16x8 v;
        #pragma unroll
        for (int j = 0; j < 8; ++j) v[j] = (short)f2b(tile[kb + j][c]);
        *reinterpret_cast<bf16x8*>(&dst[(size_t)w * 8]) = v;
    }
}

// ---------------------------------------------------------------- prep16 ---
// L4: W[e][512][128] -> 16x16x32 frag order (r10 layout).
__global__ __launch_bounds__(256)
void prep16(const float* __restrict__ Wd2, ushort* __restrict__ W4p)
{
    const int e = blockIdx.y, fg = blockIdx.x;   // fg 0..7
    constexpr int K = 512, N = 128, NK = K / 32;
    const float* W = Wd2 + (size_t)e * K * N;
    __shared__ float tile[512][17];
    const int tid = threadIdx.x;
    const int n0 = fg * 16;
    for (int idx = tid; idx < K * 16; idx += 256)
        tile[idx >> 4][idx & 15] = W[(size_t)(idx >> 4) * N + n0 + (idx & 15)];
    __syncthreads();
    ushort* dst = W4p + (((size_t)e * (N / 16) + fg) * NK) * 512;
    for (int w = tid; w < NK * 64; w += 256) {
        const int s = w >> 6, lane = w & 63;
        const int c  = lane & 15;
        const int kb = s * 32 + ((lane >> 4) << 3);
        bf16x8 v;
        #pragma unroll
        for (int j = 0; j < 8; ++j) v[j] = (short)f2b(tile[kb + j][c]);
        *reinterpret_cast<bf16x8*>(&dst[(size_t)w * 8]) = v;
    }
}

// ---------------------------------------------------- layer32 (L1,L2,L3) ---
// A: LDS [64][K] bf16, sig-swizzled. B: packed global. Output -> LDS.
// 32x32x16 swapped-operand: lane holds our-row = lane&31; acc elem 4q+t ->
// our-col = (wc*F+f)*32 + 8q + 4*(lane>>5) + t.
template<int K, int N, int MG, int RELU>
__device__ __forceinline__ void layer32(
    const ushort* __restrict__ Wp, const float* __restrict__ bias,
    const ushort* __restrict__ sIn, ushort* __restrict__ sOut,
    int wid, int lane)
{
    constexpr int NG = 16 / MG;
    constexpr int F  = N / 32 / NG;          // col frags per wave
    constexpr int M4 = 2 / MG;               // 32-row frags per wave
    constexpr int NK = K / 16;
    constexpr int SP = (M4 * F == 1) ? 2 : 1; // acc parity split (dep chain)
    const int l31 = lane & 31, hi = lane >> 5;
    const int wc = wid % NG, wr = wid / NG;
    const int rowBase = (MG == 1) ? 0 : wr * 32;

    const ushort* bBase = Wp + ((size_t)(wc * F) * NK) * 512 + (size_t)lane * 8;

    f32x16 acc[M4][F][SP];
    #pragma unroll
    for (int m = 0; m < M4; ++m)
        #pragma unroll
        for (int f = 0; f < F; ++f)
            #pragma unroll
            for (int p = 0; p < SP; ++p)
                #pragma unroll
                for (int t = 0; t < 16; ++t)
                    acc[m][f][p][t] = 0.f;

    #pragma unroll
    for (int s = 0; s < NK; ++s) {
        bf16x8 a[M4];
        #pragma unroll
        for (int m = 0; m < M4; ++m) {
            const int row  = rowBase + m * 32 + l31;
            const int phys = (2 * s + hi) ^ sig(row);
            a[m] = *reinterpret_cast<const bf16x8*>(
                reinterpret_cast<const char*>(sIn) + row * (K * 2) + (phys << 4));
        }
        bf16x8 b[F];
        #pragma unroll
        for (int f = 0; f < F; ++f)
            b[f] = *reinterpret_cast<const bf16x8*>(
                bBase + ((size_t)f * NK + s) * 512);
        #pragma unroll
        for (int m = 0; m < M4; ++m)
            #pragma unroll
            for (int f = 0; f < F; ++f) {
                const int p = (SP == 2) ? (s & 1) : 0;   // compile-time (unrolled)
                acc[m][f][p] = __builtin_amdgcn_mfma_f32_32x32x16_bf16(
                    b[f], a[m], acc[m][f][p], 0, 0, 0);
            }
    }

    // epilogue: lane -> row = rowBase+m*32+l31; cols in 4-float groups
    #pragma unroll
    for (int m = 0; m < M4; ++m) {
        const int row = rowBase + m * 32 + l31;
        #pragma unroll
        for (int f = 0; f < F; ++f) {
            #pragma unroll
            for (int q = 0; q < 4; ++q) {
                const int cbase = (wc * F + f) * 32 + 8 * q + 4 * hi;
                const float4 bq = *reinterpret_cast<const float4*>(&bias[cbase]);
                const float bArr[4] = {bq.x, bq.y, bq.z, bq.w};
                float v[4];
                #pragma unroll
                for (int t = 0; t < 4; ++t) {
                    float x = acc[m][f][0][4 * q + t];
                    if (SP == 2) x += acc[m][f][1][4 * q + t];
                    x += bArr[t];
                    if (RELU) x = fmaxf(x, 0.f);
                    v[t] = x;
                }
                const uint lo = ((uint)f2b(v[1]) << 16) | (uint)f2b(v[0]);
                const uint hh = ((uint)f2b(v[3]) << 16) | (uint)f2b(v[2]);
                const int byteoff = row * (N * 2) +
                    (((cbase >> 3) ^ sig(row)) << 4) + ((cbase & 7) << 1);
                *reinterpret_cast<uint2*>(
                    reinterpret_cast<char*>(sOut) + byteoff) = (uint2){lo, hh};
            }
        }
    }
}

// ------------------------------------------------------------ layer16 (L4) ---
// 16x16x32, (MG,NG)=(2,8), F=1, output fp32 global. r10 path + sig swizzle.
template<int K, int N, int RELU>
__device__ __forceinline__ void layer16(
    const ushort* __restrict__ Wp, const float* __restrict__ bias,
    const ushort* __restrict__ sIn, float* __restrict__ gOut,
    int wid, int lane)
{
    constexpr int NG = 8, F = N / 16 / NG, M4 = 2, NK = K / 32;
    const int r15 = lane & 15, lh = lane >> 4;
    const int wc = wid % NG, wr = wid / NG;
    const int rowBase = wr * 32;

    const ushort* bBase = Wp + ((size_t)(wc * F) * NK) * 512 + (size_t)lane * 8;

    f32x4 acc[M4][F];
    #pragma unroll
    for (int m = 0; m < M4; ++m)
        #pragma unroll
        for (int f = 0; f < F; ++f)
            acc[m][f] = (f32x4){0.f, 0.f, 0.f, 0.f};

    #pragma unroll
    for (int s = 0; s < NK; ++s) {
        bf16x8 a[M4];
        #pragma unroll
        for (int m = 0; m < M4; ++m) {
            const int row  = rowBase + m * 16 + r15;
            const int phys = (4 * s + lh) ^ sig(row);
            a[m] = *reinterpret_cast<const bf16x8*>(
                reinterpret_cast<const char*>(sIn) + row * (K * 2) + (phys << 4));
        }
        bf16x8 b[F];
        #pragma unroll
        for (int f = 0; f < F; ++f)
            b[f] = *reinterpret_cast<const bf16x8*>(
                bBase + ((size_t)f * NK + s) * 512);
        #pragma unroll
        for (int m = 0; m < M4; ++m)
            #pragma unroll
            for (int f = 0; f < F; ++f)
                acc[m][f] = __builtin_amdgcn_mfma_f32_16x16x32_bf16(
                    b[f], a[m], acc[m][f], 0, 0, 0);
    }

    #pragma unroll
    for (int f = 0; f < F; ++f) {
        const int cbase = (wc * F + f) * 16 + lh * 4;
        const float4 bq = *reinterpret_cast<const float4*>(&bias[cbase]);
        #pragma unroll
        for (int m = 0; m < M4; ++m) {
            const int row = rowBase + m * 16 + r15;
            float v0 = acc[m][f][0] + bq.x;
            float v1 = acc[m][f][1] + bq.y;
            float v2 = acc[m][f][2] + bq.z;
            float v3 = acc[m][f][3] + bq.w;
            if (RELU) {
                v0 = fmaxf(v0, 0.f); v1 = fmaxf(v1, 0.f);
                v2 = fmaxf(v2, 0.f); v3 = fmaxf(v3, 0.f);
            }
            *reinterpret_cast<float4*>(&gOut[(size_t)row * N + cbase]) =
                (float4){v0, v1, v2, v3};
        }
    }
}

// ----------------------------------------------------------- fused kernel ---
__global__ __launch_bounds__(1024, 4)
void madps_fused(const float* __restrict__ X,
                 const int* __restrict__ sel_s, const int* __restrict__ sel_d,
                 const ushort* __restrict__ W1p, const ushort* __restrict__ W2p,
                 const ushort* __restrict__ W3p, const ushort* __restrict__ W4p,
                 const float* __restrict__ bs1, const float* __restrict__ bs2,
                 const float* __restrict__ bd1, const float* __restrict__ bd2,
                 float* __restrict__ out)
{
    constexpr int S = 256, H1 = 512, H2 = 256, D1 = 512, D2 = 128;

    __shared__ __align__(16) ushort buf0[64 * 256];   // 32 KB: X, then sh
    __shared__ __align__(16) ushort buf1[64 * 512];   // 64 KB: h, then d

    const int bid   = blockIdx.x;
    const int agent = bid & 7;          // agent == XCD -> weights L2-resident
    const int rb    = bid >> 3;         // row-block within agent (0..31)
    const int tid   = threadIdx.x;
    const int lane  = tid & 63;
    const int wid   = tid >> 6;         // 0..15

    const long long es = sel_s[agent];
    const long long ed = sel_d[agent];

    const float* Xa = X + ((size_t)agent * 2048 + (size_t)rb * 64) * S;

    // ---- stage X [64][256] fp32 -> buf0 bf16 (sig-swizzled) ----
    #pragma unroll
    for (int i = 0; i < 4; ++i) {
        const int flat4 = i * 1024 + tid;       // float4 index, 64/row
        const int row = flat4 >> 6;
        const int c4  = flat4 & 63;
        const float4 v = reinterpret_cast<const float4*>(Xa)[flat4];
        ushort4 o;
        o.x = f2b(v.x); o.y = f2b(v.y); o.z = f2b(v.z); o.w = f2b(v.w);
        const int byteoff = (((c4 >> 1) ^ sig(row)) << 4) | ((c4 & 1) << 3);
        *reinterpret_cast<ushort4*>(
            reinterpret_cast<char*>(buf0) + row * 512 + byteoff) = o;
    }
    __syncthreads();

    // L1: X(buf0,K=256) @ W1p -> relu -> h(buf1,N=512)   32x32, (1,16)
    layer32<S, H1, 1, 1>(W1p + (size_t)es * (S * H1), bs1 + es * H1,
                         buf0, buf1, wid, lane);
    __syncthreads();
    // L2: h(buf1,K=512) @ W2p -> relu -> sh(buf0,N=256)  32x32, (2,8)
    layer32<H1, H2, 2, 1>(W2p + (size_t)es * (H1 * H2), bs2 + es * H2,
                          buf1, buf0, wid, lane);
    __syncthreads();
    // L3: sh(buf0,K=256) @ W3p -> relu -> d(buf1,N=512)  32x32, (1,16)
    layer32<H2, D1, 1, 1>(W3p + (size_t)ed * (H2 * D1), bd1 + ed * D1,
                          buf0, buf1, wid, lane);
    __syncthreads();
    // L4: d(buf1,K=512) @ W4p + bias -> out fp32 [64][128]  16x16, (2,8)
    float* outP = out + ((size_t)agent * 2048 + (size_t)rb * 64) * D2;
    layer16<D1, D2, 0>(W4p + (size_t)ed * (D1 * D2), bd2 + ed * D2,
                       buf1, outP, wid, lane);
}

// --------------------------------------------------------------- launch ---
extern "C" void kernel_launch(void* const* d_in, const int* in_sizes, int n_in,
                              void* d_out, int out_size, void* d_ws, size_t ws_size,
                              hipStream_t stream)
{
    constexpr int E = 8, S = 256, H1 = 512, H2 = 256, D1 = 512, D2 = 128;

    const float* inputs = (const float*)d_in[0];
    const int*   sel_s  = (const int*)d_in[1];
    const int*   sel_d  = (const int*)d_in[2];
    const float* Ws1 = (const float*)d_in[3];
    const float* bs1 = (const float*)d_in[4];
    const float* Ws2 = (const float*)d_in[5];
    const float* bs2 = (const float*)d_in[6];
    const float* Wd1 = (const float*)d_in[7];
    const float* bd1 = (const float*)d_in[8];
    const float* Wd2 = (const float*)d_in[9];
    const float* bd2 = (const float*)d_in[10];
    float* out = (float*)d_out;

    // workspace: packed bf16 weights
    ushort* W1p = (ushort*)d_ws;
    ushort* W2p = W1p + (size_t)E * S * H1;
    ushort* W3p = W2p + (size_t)E * H1 * H2;
    ushort* W4p = W3p + (size_t)E * H2 * D1;

    prep32<<<dim3(16, E, 3), 256, 0, stream>>>(Ws1, Ws2, Wd1, W1p, W2p, W3p);
    prep16<<<dim3(8, E, 1), 256, 0, stream>>>(Wd2, W4p);

    madps_fused<<<dim3(256), dim3(1024), 0, stream>>>(
        inputs, sel_s, sel_d, W1p, W2p, W3p, W4p,
        bs1, bs2, bd1, bd2, out);
}

// Round 14
// 36.049 us; speedup vs baseline: 1.0997x; 1.0997x over previous
//
#include <hip/hip_runtime.h>
#include <hip/hip_bf16.h>

// MADPSNet fused, round 14: revert to r10 (34.1us verified best) after r13's
// DMA-ring failed correctness (race, absmax 0.21) and would have added ~5us
// LDS traffic anyway. Two low-risk additions:
//  1) prep early-exit for unselected experts (~35% avg prep BW cut)
//  2) s_setprio(1) around MFMA cluster, isolated (no sched_barrier) --
//     T5's regime = wave role diversity; 16 drifting waves qualify
// Structure (all verified across r8-r12): M=64 rows/block, 256 blocks,
// 1024 thr = 16 waves = 4 waves/SIMD, col-split (MG,NG)=(1,16) [B-L2 traffic
// minimized -- r5/r11 prove multi-block/CU B-doubling regresses], packed-B
// fragment streams, swapped-operand MFMA (transposed C/D -> vector epilogue),
// XOR-swizzled LDS activations, agent=bid&7 XCD pinning.

typedef __attribute__((ext_vector_type(8))) short bf16x8;
typedef __attribute__((ext_vector_type(4))) float f32x4;

__device__ __forceinline__ ushort f2b(float x) {
    __hip_bfloat16 h = __float2bfloat16(x);
    return *reinterpret_cast<ushort*>(&h);
}

// ------------------------------------------------------------------ prep ---
// W[e][K][N] fp32 -> Wp[e][fg][s][lane][j] bf16 (MFMA fragment order):
//   n = fg*16 + (lane&15), k = s*32 + (lane>>4)*8 + j,  s = 0..K/32-1
// Early-exit: skip experts not selected by any agent (layers 0,1 use sel_s;
// layers 2,3 use sel_d). Deterministic (depends only on inputs).
__global__ __launch_bounds__(256)
void prep_weights(const float* __restrict__ Ws1, const float* __restrict__ Ws2,
                  const float* __restrict__ Wd1, const float* __restrict__ Wd2,
                  const int* __restrict__ sel_s, const int* __restrict__ sel_d,
                  ushort* __restrict__ W1p, ushort* __restrict__ W2p,
                  ushort* __restrict__ W3p, ushort* __restrict__ W4p)
{
    const int layer = blockIdx.z;
    const int e  = blockIdx.y;
    const int fg = blockIdx.x;

    const int* sel = (layer <= 1) ? sel_s : sel_d;
    bool used = false;
    #pragma unroll
    for (int a = 0; a < 8; ++a) used |= (sel[a] == e);
    if (!used) return;

    const float* W; ushort* Wp; int K, N;
    if (layer == 0)      { W = Ws1; Wp = W1p; K = 256; N = 512; }
    else if (layer == 1) { W = Ws2; Wp = W2p; K = 512; N = 256; }
    else if (layer == 2) { W = Wd1; Wp = W3p; K = 256; N = 512; }
    else                 { W = Wd2; Wp = W4p; K = 512; N = 128; }
    if (fg >= N / 16) return;
    const int NK = K / 32;
    W += (size_t)e * K * N;

    __shared__ float tile[512][17];
    const int tid = threadIdx.x;
    const int n0 = fg * 16;
    for (int idx = tid; idx < K * 16; idx += 256)
        tile[idx >> 4][idx & 15] = W[(size_t)(idx >> 4) * N + n0 + (idx & 15)];
    __syncthreads();
    ushort* dst = Wp + (((size_t)e * (N / 16) + fg) * NK) * 512;
    for (int w = tid; w < NK * 64; w += 256) {
        const int s    = w >> 6;
        const int lane = w & 63;
        const int c    = lane & 15;
        const int kb   = s * 32 + ((lane >> 4) << 3);
        bf16x8 v;
        #pragma unroll
        for (int j = 0; j < 8; ++j)
            v[j] = (short)f2b(tile[kb + j][c]);
        *reinterpret_cast<bf16x8*>(&dst[(size_t)w * 8]) = v;
    }
}

// ----------------------------------------------------------- fused layer ---
// A: LDS [64][K] bf16 swizzled. B: packed global (fragment order).
// 16 waves: MG row-groups x NG col-groups (MG*NG=16), F=N/16/NG frags/wave.
// Swapped-operand MFMA -> transposed C/D -> vector epilogue.
template<int K, int N, int MG, int RELU>
__device__ __forceinline__ void layer_mlp(
    const ushort* __restrict__ Wp, const float* __restrict__ bias,
    const ushort* __restrict__ sIn, ushort* __restrict__ sOut,
    float* __restrict__ gOut, int wid, int lane)
{
    constexpr int NG = 16 / MG;          // col groups
    constexpr int F  = N / 16 / NG;      // frags per wave
    constexpr int M4 = 4 / MG;           // m-frags per wave
    constexpr int NK = K / 32;           // k-steps
    const int r15 = lane & 15, lh = lane >> 4;
    const int wc = wid % NG, wr = wid / NG;
    const int rowBase = wr * (64 / MG);

    const ushort* bBase = Wp + ((size_t)(wc * F) * NK) * 512 + (size_t)lane * 8;

    f32x4 acc[M4][F];
    #pragma unroll
    for (int m = 0; m < M4; ++m)
        #pragma unroll
        for (int f = 0; f < F; ++f)
            acc[m][f] = (f32x4){0.f, 0.f, 0.f, 0.f};

    #pragma unroll
    for (int s = 0; s < NK; ++s) {
        const int k0 = s * 32;
        bf16x8 a[M4];
        #pragma unroll
        for (int m = 0; m < M4; ++m) {
            const int row  = rowBase + m * 16 + r15;
            const int phys = ((k0 >> 3) + lh) ^ (row & 7);
            a[m] = *reinterpret_cast<const bf16x8*>(
                reinterpret_cast<const char*>(sIn) + row * (K * 2) + (phys << 4));
        }
        bf16x8 b[F];
        #pragma unroll
        for (int f = 0; f < F; ++f)
            b[f] = *reinterpret_cast<const bf16x8*>(
                bBase + ((size_t)f * NK + s) * 512);
        // swapped operands: lane holds (row = lane&15, 4 consecutive cols)
        __builtin_amdgcn_s_setprio(1);
        #pragma unroll
        for (int m = 0; m < M4; ++m)
            #pragma unroll
            for (int f = 0; f < F; ++f)
                acc[m][f] = __builtin_amdgcn_mfma_f32_16x16x32_bf16(
                    b[f], a[m], acc[m][f], 0, 0, 0);
        __builtin_amdgcn_s_setprio(0);
    }

    // epilogue: lane holds (row = rowBase+m*16+r15, cols cbase..cbase+3)
    #pragma unroll
    for (int f = 0; f < F; ++f) {
        const int cbase = (wc * F + f) * 16 + lh * 4;
        const float4 bv = *reinterpret_cast<const float4*>(&bias[cbase]);
        #pragma unroll
        for (int m = 0; m < M4; ++m) {
            const int row = rowBase + m * 16 + r15;
            float v0 = acc[m][f][0] + bv.x;
            float v1 = acc[m][f][1] + bv.y;
            float v2 = acc[m][f][2] + bv.z;
            float v3 = acc[m][f][3] + bv.w;
            if (RELU) {
                v0 = fmaxf(v0, 0.f); v1 = fmaxf(v1, 0.f);
                v2 = fmaxf(v2, 0.f); v3 = fmaxf(v3, 0.f);
            }
            if (gOut) {
                *reinterpret_cast<float4*>(&gOut[(size_t)row * N + cbase]) =
                    (float4){v0, v1, v2, v3};
            } else {
                const uint lo = ((uint)f2b(v1) << 16) | (uint)f2b(v0);
                const uint hi = ((uint)f2b(v3) << 16) | (uint)f2b(v2);
                const int byteoff = row * (N * 2) +
                    ((((cbase >> 3) ^ (row & 7))) << 4) + ((cbase & 7) << 1);
                *reinterpret_cast<uint2*>(
                    reinterpret_cast<char*>(sOut) + byteoff) = (uint2){lo, hi};
            }
        }
    }
}

// ----------------------------------------------------------- fused kernel ---
__global__ __launch_bounds__(1024, 4)
void madps_fused(const float* __restrict__ X,
                 const int* __restrict__ sel_s, const int* __restrict__ sel_d,
                 const ushort* __restrict__ W1p, const ushort* __restrict__ W2p,
                 const ushort* __restrict__ W3p, const ushort* __restrict__ W4p,
                 const float* __restrict__ bs1, const float* __restrict__ bs2,
                 const float* __restrict__ bd1, const float* __restrict__ bd2,
                 float* __restrict__ out)
{
    constexpr int S = 256, H1 = 512, H2 = 256, D1 = 512, D2 = 128;

    __shared__ __align__(16) ushort buf0[64 * 256];   // 32 KB: X, then sh
    __shared__ __align__(16) ushort buf1[64 * 512];   // 64 KB: h, then d

    const int bid   = blockIdx.x;
    const int agent = bid & 7;          // agent == XCD -> weights L2-resident
    const int rb    = bid >> 3;         // row-block within agent (0..31)
    const int tid   = threadIdx.x;
    const int lane  = tid & 63;
    const int wid   = tid >> 6;         // 0..15

    const long long es = sel_s[agent];
    const long long ed = sel_d[agent];

    const float* Xa = X + ((size_t)agent * 2048 + (size_t)rb * 64) * S;

    // ---- stage X [64][256] fp32 -> buf0 bf16 (swizzled) ----
    #pragma unroll
    for (int i = 0; i < 4; ++i) {
        const int flat4 = i * 1024 + tid;       // float4 index, 64/row
        const int row = flat4 >> 6;
        const int c4  = flat4 & 63;
        const float4 v = reinterpret_cast<const float4*>(Xa)[flat4];
        ushort4 o;
        o.x = f2b(v.x); o.y = f2b(v.y); o.z = f2b(v.z); o.w = f2b(v.w);
        const int byteoff = (((c4 >> 1) ^ (row & 7)) << 4) | ((c4 & 1) << 3);
        *reinterpret_cast<ushort4*>(
            reinterpret_cast<char*>(buf0) + row * 512 + byteoff) = o;
    }
    __syncthreads();

    // L1: X(buf0, K=256) @ W1p -> relu -> h(buf1, N=512)
    layer_mlp<S, H1, 1, 1>(W1p + (size_t)es * ((H1 / 16) * (S / 32) * 512),
                           bs1 + es * H1, buf0, buf1, nullptr, wid, lane);
    __syncthreads();
    // L2: h(buf1, K=512) @ W2p -> relu -> sh(buf0, N=256)
    layer_mlp<H1, H2, 1, 1>(W2p + (size_t)es * ((H2 / 16) * (H1 / 32) * 512),
                            bs2 + es * H2, buf1, buf0, nullptr, wid, lane);
    __syncthreads();
    // L3: sh(buf0, K=256) @ W3p -> relu -> d(buf1, N=512)
    layer_mlp<H2, D1, 1, 1>(W3p + (size_t)ed * ((D1 / 16) * (H2 / 32) * 512),
                            bd1 + ed * D1, buf0, buf1, nullptr, wid, lane);
    __syncthreads();
    // L4: d(buf1, K=512) @ W4p + bias -> out fp32 [64][128]  (2x8 M-split)
    float* outP = out + ((size_t)agent * 2048 + (size_t)rb * 64) * D2;
    layer_mlp<D1, D2, 2, 0>(W4p + (size_t)ed * ((D2 / 16) * (D1 / 32) * 512),
                            bd2 + ed * D2, buf1, nullptr, outP, wid, lane);
}

// --------------------------------------------------------------- launch ---
extern "C" void kernel_launch(void* const* d_in, const int* in_sizes, int n_in,
                              void* d_out, int out_size, void* d_ws, size_t ws_size,
                              hipStream_t stream)
{
    constexpr int E = 8, S = 256, H1 = 512, H2 = 256, D1 = 512, D2 = 128;

    const float* inputs = (const float*)d_in[0];
    const int*   sel_s  = (const int*)d_in[1];
    const int*   sel_d  = (const int*)d_in[2];
    const float* Ws1 = (const float*)d_in[3];
    const float* bs1 = (const float*)d_in[4];
    const float* Ws2 = (const float*)d_in[5];
    const float* bs2 = (const float*)d_in[6];
    const float* Wd1 = (const float*)d_in[7];
    const float* bd1 = (const float*)d_in[8];
    const float* Wd2 = (const float*)d_in[9];
    const float* bd2 = (const float*)d_in[10];
    float* out = (float*)d_out;

    // workspace: packed bf16 weights
    ushort* W1p = (ushort*)d_ws;
    ushort* W2p = W1p + (size_t)E * S * H1;
    ushort* W3p = W2p + (size_t)E * H1 * H2;
    ushort* W4p = W3p + (size_t)E * H2 * D1;

    prep_weights<<<dim3(32, E, 4), 256, 0, stream>>>(
        Ws1, Ws2, Wd1, Wd2, sel_s, sel_d, W1p, W2p, W3p, W4p);

    madps_fused<<<dim3(256), dim3(1024), 0, stream>>>(
        inputs, sel_s, sel_d, W1p, W2p, W3p, W4p,
        bs1, bs2, bd1, bd2, out);
}

// Round 15
// 33.697 us; speedup vs baseline: 1.1764x; 1.0698x over previous
//
#include <hip/hip_runtime.h>
#include <hip/hip_bf16.h>

// MADPSNet fused, round 15: r10 EXACT (34.1us verified best) + prep
// early-exit only. r14 attribution: setprio cost 2-3us (T5 harmful in
// intra-layer lockstep — matches m190 GEMM null, not m191 attn); early-exit
// is strictly-positive prep work removal. Scheduling-class levers now 0/4 —
// closed. Structure (verified r8-r12): M=64 rows/block, 256 blocks, 1024 thr
// = 16 waves = 4 waves/SIMD, col-split (MG,NG)=(1,16) [minimizes B-L2; r5/r11
// prove B-doubling regresses super-linearly], packed-B fragment streams,
// swapped-operand MFMA (transposed C/D -> vector epilogue), XOR-swizzled LDS
// activations, agent=bid&7 XCD pinning.

typedef __attribute__((ext_vector_type(8))) short bf16x8;
typedef __attribute__((ext_vector_type(4))) float f32x4;

__device__ __forceinline__ ushort f2b(float x) {
    __hip_bfloat16 h = __float2bfloat16(x);
    return *reinterpret_cast<ushort*>(&h);
}

// ------------------------------------------------------------------ prep ---
// W[e][K][N] fp32 -> Wp[e][fg][s][lane][j] bf16 (MFMA fragment order):
//   n = fg*16 + (lane&15), k = s*32 + (lane>>4)*8 + j,  s = 0..K/32-1
// Early-exit: skip experts not selected by any agent (layers 0,1 use sel_s;
// layers 2,3 use sel_d). Deterministic (pure function of inputs).
__global__ __launch_bounds__(256)
void prep_weights(const float* __restrict__ Ws1, const float* __restrict__ Ws2,
                  const float* __restrict__ Wd1, const float* __restrict__ Wd2,
                  const int* __restrict__ sel_s, const int* __restrict__ sel_d,
                  ushort* __restrict__ W1p, ushort* __restrict__ W2p,
                  ushort* __restrict__ W3p, ushort* __restrict__ W4p)
{
    const int layer = blockIdx.z;
    const int e  = blockIdx.y;
    const int fg = blockIdx.x;

    const int* sel = (layer <= 1) ? sel_s : sel_d;
    bool used = false;
    #pragma unroll
    for (int a = 0; a < 8; ++a) used |= (sel[a] == e);
    if (!used) return;

    const float* W; ushort* Wp; int K, N;
    if (layer == 0)      { W = Ws1; Wp = W1p; K = 256; N = 512; }
    else if (layer == 1) { W = Ws2; Wp = W2p; K = 512; N = 256; }
    else if (layer == 2) { W = Wd1; Wp = W3p; K = 256; N = 512; }
    else                 { W = Wd2; Wp = W4p; K = 512; N = 128; }
    if (fg >= N / 16) return;
    const int NK = K / 32;
    W += (size_t)e * K * N;

    __shared__ float tile[512][17];
    const int tid = threadIdx.x;
    const int n0 = fg * 16;
    for (int idx = tid; idx < K * 16; idx += 256)
        tile[idx >> 4][idx & 15] = W[(size_t)(idx >> 4) * N + n0 + (idx & 15)];
    __syncthreads();
    ushort* dst = Wp + (((size_t)e * (N / 16) + fg) * NK) * 512;
    for (int w = tid; w < NK * 64; w += 256) {
        const int s    = w >> 6;
        const int lane = w & 63;
        const int c    = lane & 15;
        const int kb   = s * 32 + ((lane >> 4) << 3);
        bf16x8 v;
        #pragma unroll
        for (int j = 0; j < 8; ++j)
            v[j] = (short)f2b(tile[kb + j][c]);
        *reinterpret_cast<bf16x8*>(&dst[(size_t)w * 8]) = v;
    }
}

// ----------------------------------------------------------- fused layer ---
// A: LDS [64][K] bf16 swizzled. B: packed global (fragment order).
// 16 waves: MG row-groups x NG col-groups (MG*NG=16), F=N/16/NG frags/wave.
// Swapped-operand MFMA -> transposed C/D -> vector epilogue.
template<int K, int N, int MG, int RELU>
__device__ __forceinline__ void layer_mlp(
    const ushort* __restrict__ Wp, const float* __restrict__ bias,
    const ushort* __restrict__ sIn, ushort* __restrict__ sOut,
    float* __restrict__ gOut, int wid, int lane)
{
    constexpr int NG = 16 / MG;          // col groups
    constexpr int F  = N / 16 / NG;      // frags per wave
    constexpr int M4 = 4 / MG;           // m-frags per wave
    constexpr int NK = K / 32;           // k-steps
    const int r15 = lane & 15, lh = lane >> 4;
    const int wc = wid % NG, wr = wid / NG;
    const int rowBase = wr * (64 / MG);

    const ushort* bBase = Wp + ((size_t)(wc * F) * NK) * 512 + (size_t)lane * 8;

    f32x4 acc[M4][F];
    #pragma unroll
    for (int m = 0; m < M4; ++m)
        #pragma unroll
        for (int f = 0; f < F; ++f)
            acc[m][f] = (f32x4){0.f, 0.f, 0.f, 0.f};

    #pragma unroll
    for (int s = 0; s < NK; ++s) {
        const int k0 = s * 32;
        bf16x8 a[M4];
        #pragma unroll
        for (int m = 0; m < M4; ++m) {
            const int row  = rowBase + m * 16 + r15;
            const int phys = ((k0 >> 3) + lh) ^ (row & 7);
            a[m] = *reinterpret_cast<const bf16x8*>(
                reinterpret_cast<const char*>(sIn) + row * (K * 2) + (phys << 4));
        }
        bf16x8 b[F];
        #pragma unroll
        for (int f = 0; f < F; ++f)
            b[f] = *reinterpret_cast<const bf16x8*>(
                bBase + ((size_t)f * NK + s) * 512);
        // swapped operands: lane holds (row = lane&15, 4 consecutive cols)
        #pragma unroll
        for (int m = 0; m < M4; ++m)
            #pragma unroll
            for (int f = 0; f < F; ++f)
                acc[m][f] = __builtin_amdgcn_mfma_f32_16x16x32_bf16(
                    b[f], a[m], acc[m][f], 0, 0, 0);
    }

    // epilogue: lane holds (row = rowBase+m*16+r15, cols cbase..cbase+3)
    #pragma unroll
    for (int f = 0; f < F; ++f) {
        const int cbase = (wc * F + f) * 16 + lh * 4;
        const float4 bv = *reinterpret_cast<const float4*>(&bias[cbase]);
        #pragma unroll
        for (int m = 0; m < M4; ++m) {
            const int row = rowBase + m * 16 + r15;
            float v0 = acc[m][f][0] + bv.x;
            float v1 = acc[m][f][1] + bv.y;
            float v2 = acc[m][f][2] + bv.z;
            float v3 = acc[m][f][3] + bv.w;
            if (RELU) {
                v0 = fmaxf(v0, 0.f); v1 = fmaxf(v1, 0.f);
                v2 = fmaxf(v2, 0.f); v3 = fmaxf(v3, 0.f);
            }
            if (gOut) {
                *reinterpret_cast<float4*>(&gOut[(size_t)row * N + cbase]) =
                    (float4){v0, v1, v2, v3};
            } else {
                const uint lo = ((uint)f2b(v1) << 16) | (uint)f2b(v0);
                const uint hi = ((uint)f2b(v3) << 16) | (uint)f2b(v2);
                const int byteoff = row * (N * 2) +
                    ((((cbase >> 3) ^ (row & 7))) << 4) + ((cbase & 7) << 1);
                *reinterpret_cast<uint2*>(
                    reinterpret_cast<char*>(sOut) + byteoff) = (uint2){lo, hi};
            }
        }
    }
}

// ----------------------------------------------------------- fused kernel ---
__global__ __launch_bounds__(1024, 4)
void madps_fused(const float* __restrict__ X,
                 const int* __restrict__ sel_s, const int* __restrict__ sel_d,
                 const ushort* __restrict__ W1p, const ushort* __restrict__ W2p,
                 const ushort* __restrict__ W3p, const ushort* __restrict__ W4p,
                 const float* __restrict__ bs1, const float* __restrict__ bs2,
                 const float* __restrict__ bd1, const float* __restrict__ bd2,
                 float* __restrict__ out)
{
    constexpr int S = 256, H1 = 512, H2 = 256, D1 = 512, D2 = 128;

    __shared__ __align__(16) ushort buf0[64 * 256];   // 32 KB: X, then sh
    __shared__ __align__(16) ushort buf1[64 * 512];   // 64 KB: h, then d

    const int bid   = blockIdx.x;
    const int agent = bid & 7;          // agent == XCD -> weights L2-resident
    const int rb    = bid >> 3;         // row-block within agent (0..31)
    const int tid   = threadIdx.x;
    const int lane  = tid & 63;
    const int wid   = tid >> 6;         // 0..15

    const long long es = sel_s[agent];
    const long long ed = sel_d[agent];

    const float* Xa = X + ((size_t)agent * 2048 + (size_t)rb * 64) * S;

    // ---- stage X [64][256] fp32 -> buf0 bf16 (swizzled) ----
    #pragma unroll
    for (int i = 0; i < 4; ++i) {
        const int flat4 = i * 1024 + tid;       // float4 index, 64/row
        const int row = flat4 >> 6;
        const int c4  = flat4 & 63;
        const float4 v = reinterpret_cast<const float4*>(Xa)[flat4];
        ushort4 o;
        o.x = f2b(v.x); o.y = f2b(v.y); o.z = f2b(v.z); o.w = f2b(v.w);
        const int byteoff = (((c4 >> 1) ^ (row & 7)) << 4) | ((c4 & 1) << 3);
        *reinterpret_cast<ushort4*>(
            reinterpret_cast<char*>(buf0) + row * 512 + byteoff) = o;
    }
    __syncthreads();

    // L1: X(buf0, K=256) @ W1p -> relu -> h(buf1, N=512)
    layer_mlp<S, H1, 1, 1>(W1p + (size_t)es * ((H1 / 16) * (S / 32) * 512),
                           bs1 + es * H1, buf0, buf1, nullptr, wid, lane);
    __syncthreads();
    // L2: h(buf1, K=512) @ W2p -> relu -> sh(buf0, N=256)
    layer_mlp<H1, H2, 1, 1>(W2p + (size_t)es * ((H2 / 16) * (H1 / 32) * 512),
                            bs2 + es * H2, buf1, buf0, nullptr, wid, lane);
    __syncthreads();
    // L3: sh(buf0, K=256) @ W3p -> relu -> d(buf1, N=512)
    layer_mlp<H2, D1, 1, 1>(W3p + (size_t)ed * ((D1 / 16) * (H2 / 32) * 512),
                            bd1 + ed * D1, buf0, buf1, nullptr, wid, lane);
    __syncthreads();
    // L4: d(buf1, K=512) @ W4p + bias -> out fp32 [64][128]  (2x8 M-split)
    float* outP = out + ((size_t)agent * 2048 + (size_t)rb * 64) * D2;
    layer_mlp<D1, D2, 2, 0>(W4p + (size_t)ed * ((D2 / 16) * (D1 / 32) * 512),
                            bd2 + ed * D2, buf1, nullptr, outP, wid, lane);
}

// --------------------------------------------------------------- launch ---
extern "C" void kernel_launch(void* const* d_in, const int* in_sizes, int n_in,
                              void* d_out, int out_size, void* d_ws, size_t ws_size,
                              hipStream_t stream)
{
    constexpr int E = 8, S = 256, H1 = 512, H2 = 256, D1 = 512, D2 = 128;

    const float* inputs = (const float*)d_in[0];
    const int*   sel_s  = (const int*)d_in[1];
    const int*   sel_d  = (const int*)d_in[2];
    const float* Ws1 = (const float*)d_in[3];
    const float* bs1 = (const float*)d_in[4];
    const float* Ws2 = (const float*)d_in[5];
    const float* bs2 = (const float*)d_in[6];
    const float* Wd1 = (const float*)d_in[7];
    const float* bd1 = (const float*)d_in[8];
    const float* Wd2 = (const float*)d_in[9];
    const float* bd2 = (const float*)d_in[10];
    float* out = (float*)d_out;

    // workspace: packed bf16 weights
    ushort* W1p = (ushort*)d_ws;
    ushort* W2p = W1p + (size_t)E * S * H1;
    ushort* W3p = W2p + (size_t)E * H1 * H2;
    ushort* W4p = W3p + (size_t)E * H2 * D1;

    prep_weights<<<dim3(32, E, 4), 256, 0, stream>>>(
        Ws1, Ws2, Wd1, Wd2, sel_s, sel_d, W1p, W2p, W3p, W4p);

    madps_fused<<<dim3(256), dim3(1024), 0, stream>>>(
        inputs, sel_s, sel_d, W1p, W2p, W3p, W4p,
        bs1, bs2, bd1, bd2, out);
}